// Round 2
// baseline (6603.287 us; speedup 1.0000x reference)
//
#include <hip/hip_runtime.h>
#include <cmath>

typedef unsigned short u16;
typedef short bf16x8 __attribute__((ext_vector_type(8)));
typedef float f32x4 __attribute__((ext_vector_type(4)));

#define S_N 1025
#define W_N 128
#define H_N 200
#define FH_N 800
#define KP 224      // padded A-staging row stride (u16); 224*2=448B, 16B-aligned; holds k up to 223
#define MID 512
#define WELEM 160000   // 800*200 per weight matrix

__device__ __forceinline__ float bf2f(u16 u) {
  unsigned int x = ((unsigned int)u) << 16;
  return __builtin_bit_cast(float, x);
}
__device__ __forceinline__ u16 f2bf(float f) {
  unsigned int x = __builtin_bit_cast(unsigned int, f);
  x += 0x7fffu + ((x >> 16) & 1u);
  return (u16)(x >> 16);
}
__device__ __forceinline__ float sigm(float x) { return 1.0f / (1.0f + expf(-x)); }

// ---------------------------------------------------------------------------
// Kernel 0: round the 6 MFMA-consumed fp32 weight matrices to bf16 in ws.
// dst layout: [wih_ctx | whh_ctx | wih_tgt | whh_tgt | whh_prev | whh_post]
// ---------------------------------------------------------------------------
__global__ __launch_bounds__(256) void k_w2b(
    const float* __restrict__ a, const float* __restrict__ b,
    const float* __restrict__ c, const float* __restrict__ d,
    const float* __restrict__ e, const float* __restrict__ f,
    u16* __restrict__ dst)
{
  int i = blockIdx.x * 256 + threadIdx.x;
  if (i >= 6 * WELEM) return;
  int w = i / WELEM, r = i - w * WELEM;
  const float* ps[6] = {a, b, c, d, e, f};
  dst[i] = f2bf(ps[w][r]);
}

// ---------------------------------------------------------------------------
// Kernel 1: word-level LSTM, 16 sentences/block (blocks 0..64) + target LSTM
// for the middle sentence (block 65). Writes emb[s][0:200] fp32 at
// t == lengths[s]-1.  gates = [xhi|xlo|hhi|hlo] @ [Wih;Wih;Whh;Whh]^T via
// MFMA 16x16x32 bf16 streaming bf16 weights from L2. x and h are fp32 values
// carried as hi+lo bf16 splits; weights bf16-rounded (only quantization).
// LDS kept < 64KB: sG holds 8 sentence-rows, consumed in two half-passes.
// ---------------------------------------------------------------------------
__global__ __launch_bounds__(256) void k_word(
    const float* __restrict__ words, const int* __restrict__ lengths,
    const float* __restrict__ h0w, const float* __restrict__ c0w,
    const u16* __restrict__ wihb_ctx, const u16* __restrict__ whhb_ctx,
    const float* __restrict__ bih_ctx, const float* __restrict__ bhh_ctx,
    const u16* __restrict__ wihb_tgt, const u16* __restrict__ whhb_tgt,
    const float* __restrict__ bih_tgt, const float* __restrict__ bhh_tgt,
    float* __restrict__ emb)
{
  const int tid = threadIdx.x;
  const int b = blockIdx.x;
  const bool is_tgt = (b == 65);
  const u16* wih = is_tgt ? wihb_tgt : wihb_ctx;
  const u16* whh = is_tgt ? whhb_tgt : whhb_ctx;
  const float* bih = is_tgt ? bih_tgt : bih_ctx;
  const float* bhh = is_tgt ? bhh_tgt : bhh_ctx;

  __shared__ __align__(16) u16 sXhi[16 * KP];
  __shared__ __align__(16) u16 sXlo[16 * KP];
  __shared__ __align__(16) u16 sHi[16 * KP];
  __shared__ __align__(16) u16 sLo[16 * KP];
  __shared__ float sG[8 * 801];   // 8 sentence-rows per half; stride 801 -> no bank conflicts
  __shared__ int sLen[16];

  float creg[16];                 // cell state, per hidden unit (threads 0..199)

  for (int e = tid; e < 16 * KP; e += 256) {
    sXhi[e] = 0; sXlo[e] = 0; sHi[e] = 0; sLo[e] = 0;   // pads k>=200 stay 0
  }
  if (tid < 16) {
    int s = is_tgt ? MID : min(b * 16 + tid, S_N - 1);
    sLen[tid] = lengths[s];
  }
  if (tid < H_N) {
#pragma unroll
    for (int m = 0; m < 16; ++m) {
      int s = is_tgt ? MID : min(b * 16 + m, S_N - 1);
      float h = h0w[(size_t)s * H_N + tid];
      u16 hh = f2bf(h);
      sHi[m * KP + tid] = hh;
      sLo[m * KP + tid] = f2bf(h - bf2f(hh));
      creg[m] = c0w[(size_t)s * H_N + tid];
    }
  }
  __syncthreads();
  int Lmax = 1;
  for (int m = 0; m < 16; ++m) Lmax = max(Lmax, sLen[m]);

  const int lane = tid & 63;
  const int wv = tid >> 6;
  const int quad = lane >> 4;
  const int col = lane & 15;

  float bi = 0.f, bff = 0.f, bg = 0.f, bo = 0.f;
  if (tid < H_N) {
    bi  = bih[tid]           + bhh[tid];
    bff = bih[H_N + tid]     + bhh[H_N + tid];
    bg  = bih[2 * H_N + tid] + bhh[2 * H_N + tid];
    bo  = bih[3 * H_N + tid] + bhh[3 * H_N + tid];
  }

  // A-fragment bases: A[m = lane&15][k = quad*8 + j]
  const u16* aXh = sXhi + col * KP + quad * 8;
  const u16* aXl = sXlo + col * KP + quad * 8;
  const u16* aHh = sHi  + col * KP + quad * 8;
  const u16* aHl = sLo  + col * KP + quad * 8;

  const bf16x8 zz = {};

#pragma unroll 1
  for (int t = 0; t < Lmax; ++t) {
    // stage x_t (fp32 -> hi/lo bf16) for the 16 sentences
    for (int e = tid; e < 16 * H_N; e += 256) {
      int m = e / H_N;
      int k = e - m * H_N;
      int s = is_tgt ? MID : min(b * 16 + m, S_N - 1);
      float v = words[((size_t)s * W_N + t) * H_N + k];
      u16 vh = f2bf(v);
      sXhi[m * KP + k] = vh;
      sXlo[m * KP + k] = f2bf(v - bf2f(vh));
    }
    __syncthreads();

    f32x4 acc[13];
#pragma unroll
    for (int i = 0; i < 13; ++i) { f32x4 z4 = {0.f, 0.f, 0.f, 0.f}; acc[i] = z4; }

#pragma unroll
    for (int kcc = 0; kcc < 7; ++kcc) {
      bf16x8 axh = *(const bf16x8*)(aXh + kcc * 32);
      bf16x8 axl = *(const bf16x8*)(aXl + kcc * 32);
      bf16x8 ahh = *(const bf16x8*)(aHh + kcc * 32);
      bf16x8 ahl = *(const bf16x8*)(aHl + kcc * 32);
      const bool ktail = (kcc == 6) && (quad > 0);   // k >= 200: A pads are 0, keep B in-bounds
      const int koff = kcc * 32 + quad * 8;
#pragma unroll
      for (int i = 0; i < 13; ++i) {
        int tt = wv + 4 * i;            // this wave's n-tiles (< 50)
        if (tt < 50) {
          int gate = tt * 16 + col;     // B[n = lane&15][k]: n = gate row of W
          const u16* wp = ktail ? wih : (wih + gate * H_N + koff);
          bf16x8 bv = *(const bf16x8*)wp;
          bv = ktail ? zz : bv;
          acc[i] = __builtin_amdgcn_mfma_f32_16x16x32_bf16(axh, bv, acc[i], 0, 0, 0);
          acc[i] = __builtin_amdgcn_mfma_f32_16x16x32_bf16(axl, bv, acc[i], 0, 0, 0);
          const u16* hp = ktail ? whh : (whh + gate * H_N + koff);
          bf16x8 hv = *(const bf16x8*)hp;
          hv = ktail ? zz : hv;
          acc[i] = __builtin_amdgcn_mfma_f32_16x16x32_bf16(ahh, hv, acc[i], 0, 0, 0);
          acc[i] = __builtin_amdgcn_mfma_f32_16x16x32_bf16(ahl, hv, acc[i], 0, 0, 0);
        }
      }
    }

    // D[row][col]: row = quad*4 + r (sentence), col = lane&15 (gate in tile).
    // Two half-passes of 8 sentence-rows through the 8-row sG buffer.
#pragma unroll
    for (int h = 0; h < 2; ++h) {
      if ((quad >> 1) == h) {
#pragma unroll
        for (int i = 0; i < 13; ++i) {
          int tt = wv + 4 * i;
          if (tt < 50) {
#pragma unroll
            for (int r = 0; r < 4; ++r)
              sG[((quad & 1) * 4 + r) * 801 + tt * 16 + col] = acc[i][r];
          }
        }
      }
      __syncthreads();
      if (tid < H_N) {
        const int j = tid;
#pragma unroll
        for (int mm = 0; mm < 8; ++mm) {
          const int m = h * 8 + mm;
          float ig = sG[mm * 801 + j] + bi;
          float fg = sG[mm * 801 + H_N + j] + bff;
          float gg = sG[mm * 801 + 2 * H_N + j] + bg;
          float og = sG[mm * 801 + 3 * H_N + j] + bo;
          float nc = sigm(fg) * creg[m] + sigm(ig) * tanhf(gg);
          float nh = sigm(og) * tanhf(nc);
          creg[m] = nc;
          u16 hh = f2bf(nh);
          sHi[m * KP + j] = hh;
          sLo[m * KP + j] = f2bf(nh - bf2f(hh));
          if (t == sLen[m] - 1) {
            if (is_tgt) {
              if (m == 0) emb[(size_t)MID * H_N + j] = nh;
            } else {
              int s = min(b * 16 + m, S_N - 1);
              if (s != MID) emb[(size_t)s * H_N + j] = nh;  // tgt block owns mid
            }
          }
        }
      }
      __syncthreads();
    }
  }
}

// ---------------------------------------------------------------------------
// Kernel 2: input projections for prev/post sentence LSTMs, fp32 exact.
// gxp[t] = emb[t] @ wih_prev^T + b ; gxq[t] = emb[1024-t] @ wih_post^T + b
// ---------------------------------------------------------------------------
__global__ __launch_bounds__(256) void k_gx(
    const float* __restrict__ emb,
    const float* __restrict__ wih_prev, const float* __restrict__ bih_prev, const float* __restrict__ bhh_prev,
    const float* __restrict__ wih_post, const float* __restrict__ bih_post, const float* __restrict__ bhh_post,
    float* __restrict__ gxp, float* __restrict__ gxq)
{
  const int tid = threadIdx.x;
  const int b = blockIdx.x;
  const bool post = (b >= 513);
  const int t = post ? b - 513 : b;
  const float* erow = emb + (size_t)(post ? (1024 - t) : t) * H_N;
  const float* wih = post ? wih_post : wih_prev;
  const float* bih = post ? bih_post : bih_prev;
  const float* bhh = post ? bhh_post : bhh_prev;
  float* out = (post ? gxq : gxp) + (size_t)t * FH_N;

  __shared__ float se[H_N];
  if (tid < H_N) se[tid] = erow[tid];
  __syncthreads();
  for (int j = tid; j < FH_N; j += 256) {
    float d = bih[j] + bhh[j];
    const float* wr = wih + (size_t)j * H_N;
    for (int k = 0; k < H_N; ++k) d += wr[k] * se[k];
    out[j] = d;
  }
}

// ---------------------------------------------------------------------------
// Kernel 3: prev (block 0) and post (block 1) sentence LSTMs. 513 serial
// steps, batch=1. Whh bf16 register-resident as MFMA A-fragments. GEMV per
// step with mixed B: cols 0..7 = h_hi, cols 8..15 = h_lo; gate = D[.,c]+D[.,c^8].
// ---------------------------------------------------------------------------
__global__ __launch_bounds__(256, 1) void k_sent(
    const u16* __restrict__ whhb_prev, const u16* __restrict__ whhb_post,
    const float* __restrict__ h0p, const float* __restrict__ c0p,
    const float* __restrict__ h0q, const float* __restrict__ c0q,
    const float* __restrict__ gxp, const float* __restrict__ gxq,
    float* __restrict__ outp, float* __restrict__ outq)
{
  const int tid = threadIdx.x;
  const bool post = (blockIdx.x != 0);
  const u16* whh = post ? whhb_post : whhb_prev;
  const float* h0 = post ? h0q : h0p;
  const float* c0 = post ? c0q : c0p;
  const float* gx = post ? gxq : gxp;
  float* outv = post ? outq : outp;

  __shared__ __align__(16) u16 sHi[224];
  __shared__ __align__(16) u16 sLo[224];
  __shared__ float sG[FH_N];

  const int lane = tid & 63;
  const int wv = tid >> 6;
  const int quad = lane >> 4;
  const int col = lane & 15;

  const bf16x8 zz = {};
  // A-frags: A[m = lane&15][k = quad*8+j] = whh[tt*16 + m][k]
  bf16x8 afr[13][7];
#pragma unroll
  for (int i = 0; i < 13; ++i) {
    int tt = wv + 4 * i;
#pragma unroll
    for (int kcc = 0; kcc < 7; ++kcc) {
      int k0 = kcc * 32 + quad * 8;
      bool valid = (tt < 50) && (k0 < H_N);
      const u16* p = valid ? (whh + (tt * 16 + col) * H_N + k0) : whh;
      bf16x8 v = *(const bf16x8*)p;
      afr[i][kcc] = valid ? v : zz;
    }
  }

  if (tid < 224) { sHi[tid] = 0; sLo[tid] = 0; }
  float c = 0.f, last_h = 0.f;
  if (tid < H_N) {
    float h = h0[tid];
    u16 hh = f2bf(h);
    sHi[tid] = hh;
    sLo[tid] = f2bf(h - bf2f(hh));
    c = c0[tid];
  }
  __syncthreads();

  // B base: cols 0..7 read h_hi, cols 8..15 read h_lo
  const u16* hb = ((lane & 8) ? sLo : sHi) + quad * 8;

#pragma unroll 1
  for (int t = 0; t < 513; ++t) {
    // prefetch this step's gx early (used after the MFMA phase)
    float g0 = 0.f, g1 = 0.f, g2 = 0.f, g3 = 0.f;
    if (tid < H_N) {
      const float* g = gx + (size_t)t * FH_N;
      g0 = g[tid]; g1 = g[H_N + tid]; g2 = g[2 * H_N + tid]; g3 = g[3 * H_N + tid];
    }

    bf16x8 bfr[7];
#pragma unroll
    for (int kcc = 0; kcc < 7; ++kcc) bfr[kcc] = *(const bf16x8*)(hb + kcc * 32);

#pragma unroll
    for (int i = 0; i < 13; ++i) {
      int tt = wv + 4 * i;
      f32x4 acc = {0.f, 0.f, 0.f, 0.f};
#pragma unroll
      for (int kcc = 0; kcc < 7; ++kcc)
        acc = __builtin_amdgcn_mfma_f32_16x16x32_bf16(afr[i][kcc], bfr[kcc], acc, 0, 0, 0);
      if (tt < 50) {
#pragma unroll
        for (int r = 0; r < 4; ++r) {
          float v = acc[r];
          float v2 = __shfl_xor(v, 8);     // pair col c <-> c^8: hi + lo parts
          if (col == 0) sG[tt * 16 + quad * 4 + r] = v + v2;
        }
      }
    }
    __syncthreads();

    if (tid < H_N) {
      float ig = sG[tid] + g0;
      float fg = sG[H_N + tid] + g1;
      float gg = sG[2 * H_N + tid] + g2;
      float og = sG[3 * H_N + tid] + g3;
      float nc = sigm(fg) * c + sigm(ig) * tanhf(gg);
      float nh = sigm(og) * tanhf(nc);
      c = nc;
      last_h = nh;
      u16 hh = f2bf(nh);
      sHi[tid] = hh;
      sLo[tid] = f2bf(nh - bf2f(hh));
    }
    __syncthreads();
  }
  if (tid < H_N) outv[tid] = last_h;
}

// ---------------------------------------------------------------------------
// Kernel 4: out = [prev_out ; post_out] @ fc_w^T + fc_b  (fp32 exact)
// ---------------------------------------------------------------------------
__global__ __launch_bounds__(256) void k_fc(
    const float* __restrict__ pout, const float* __restrict__ qout,
    const float* __restrict__ fc_w, const float* __restrict__ fc_b,
    float* __restrict__ out)
{
  const int tid = threadIdx.x;
  if (tid < H_N) {
    float d = fc_b[tid];
    const float* wr = fc_w + (size_t)tid * 2 * H_N;
    for (int k = 0; k < H_N; ++k) d += pout[k] * wr[k];
    for (int k = 0; k < H_N; ++k) d += qout[k] * wr[H_N + k];
    out[tid] = d;
  }
}

extern "C" void kernel_launch(void* const* d_in, const int* in_sizes, int n_in,
                              void* d_out, int out_size, void* d_ws, size_t ws_size,
                              hipStream_t stream) {
  const float* words   = (const float*)d_in[0];
  const int*   lengths = (const int*)d_in[1];
  const float* h0w = (const float*)d_in[2];
  const float* c0w = (const float*)d_in[3];
  const float* h0p = (const float*)d_in[4];
  const float* c0p = (const float*)d_in[5];
  const float* h0q = (const float*)d_in[6];
  const float* c0q = (const float*)d_in[7];
  const float* wih_ctx = (const float*)d_in[8];
  const float* whh_ctx = (const float*)d_in[9];
  const float* bih_ctx = (const float*)d_in[10];
  const float* bhh_ctx = (const float*)d_in[11];
  const float* wih_tgt = (const float*)d_in[12];
  const float* whh_tgt = (const float*)d_in[13];
  const float* bih_tgt = (const float*)d_in[14];
  const float* bhh_tgt = (const float*)d_in[15];
  const float* wih_prev = (const float*)d_in[16];
  const float* whh_prev = (const float*)d_in[17];
  const float* bih_prev = (const float*)d_in[18];
  const float* bhh_prev = (const float*)d_in[19];
  const float* wih_post = (const float*)d_in[20];
  const float* whh_post = (const float*)d_in[21];
  const float* bih_post = (const float*)d_in[22];
  const float* bhh_post = (const float*)d_in[23];
  const float* fc_w = (const float*)d_in[24];
  const float* fc_b = (const float*)d_in[25];

  float* ws = (float*)d_ws;
  float* emb = ws;                 // 1025*200 = 205000 floats
  float* gxp = ws + 205000;        // 513*800  = 410400 floats
  float* gxq = ws + 615400;        // 513*800  = 410400 floats
  float* po  = ws + 1025800;       // 200 floats
  float* qo  = ws + 1026000;       // 200 floats
  u16* wb = (u16*)(ws + 1026200);  // 6*160000 u16 (bf16 weights)
  u16* wihb_ctx = wb;
  u16* whhb_ctx = wb + WELEM;
  u16* wihb_tgt = wb + 2 * WELEM;
  u16* whhb_tgt = wb + 3 * WELEM;
  u16* whhb_prev = wb + 4 * WELEM;
  u16* whhb_post = wb + 5 * WELEM;
  (void)in_sizes; (void)n_in; (void)out_size; (void)ws_size;

  k_w2b<<<(6 * WELEM + 255) / 256, 256, 0, stream>>>(
      wih_ctx, whh_ctx, wih_tgt, whh_tgt, whh_prev, whh_post, wb);
  k_word<<<66, 256, 0, stream>>>(words, lengths, h0w, c0w,
                                 wihb_ctx, whhb_ctx, bih_ctx, bhh_ctx,
                                 wihb_tgt, whhb_tgt, bih_tgt, bhh_tgt, emb);
  k_gx<<<1026, 256, 0, stream>>>(emb, wih_prev, bih_prev, bhh_prev,
                                 wih_post, bih_post, bhh_post, gxp, gxq);
  k_sent<<<2, 256, 0, stream>>>(whhb_prev, whhb_post, h0p, c0p, h0q, c0q,
                                gxp, gxq, po, qo);
  k_fc<<<1, 256, 0, stream>>>(po, qo, fc_w, fc_b, (float*)d_out);
}

// Round 3
// 3854.819 us; speedup vs baseline: 1.7130x; 1.7130x over previous
//
#include <hip/hip_runtime.h>
#include <cmath>

typedef unsigned short u16;
typedef short bf16x8 __attribute__((ext_vector_type(8)));
typedef float f32x4 __attribute__((ext_vector_type(4)));

#define S_N 1025
#define W_N 128
#define H_N 200
#define FH_N 800
#define KP 232       // A-staging row stride in u16 (464B): 116 dw % 32 = 20 -> ~2-way LDS conflicts
#define SGP 811      // sG row stride in floats (odd vs 32 banks)
#define MID 512
#define WELEM 160000 // 800*200 per weight matrix

__device__ __forceinline__ float bf2f(u16 u) {
  unsigned int x = ((unsigned int)u) << 16;
  return __builtin_bit_cast(float, x);
}
__device__ __forceinline__ u16 f2bf(float f) {
  unsigned int x = __builtin_bit_cast(unsigned int, f);
  x += 0x7fffu + ((x >> 16) & 1u);
  return (u16)(x >> 16);
}
#define LOG2E 1.44269504088896f
__device__ __forceinline__ float fsigm(float x) {
  float e = __builtin_amdgcn_exp2f(-fabsf(x) * LOG2E);
  float p = __builtin_amdgcn_rcpf(1.f + e);
  return x >= 0.f ? p : 1.f - p;
}
__device__ __forceinline__ float ftanh(float x) {
  float e = __builtin_amdgcn_exp2f(-2.f * fabsf(x) * LOG2E);
  float th = (1.f - e) * __builtin_amdgcn_rcpf(1.f + e);
  return x >= 0.f ? th : -th;
}

// ---------------------------------------------------------------------------
// Kernel 0: round the 8 MFMA-consumed fp32 weight matrices to bf16 in ws.
// dst: [wih_ctx|whh_ctx|wih_tgt|whh_tgt|whh_prev|whh_post|wih_prev|wih_post]
// ---------------------------------------------------------------------------
__global__ __launch_bounds__(256) void k_w2b(
    const float* __restrict__ p0, const float* __restrict__ p1,
    const float* __restrict__ p2, const float* __restrict__ p3,
    const float* __restrict__ p4, const float* __restrict__ p5,
    const float* __restrict__ p6, const float* __restrict__ p7,
    u16* __restrict__ dst)
{
  int i = blockIdx.x * 256 + threadIdx.x;
  if (i >= 8 * WELEM) return;
  int w = i / WELEM, r = i - w * WELEM;
  const float* ps[8] = {p0, p1, p2, p3, p4, p5, p6, p7};
  dst[i] = f2bf(ps[w][r]);
}

// ---------------------------------------------------------------------------
// Kernel 0b: bitonic sort of sentence ids by length (descending) -> order[].
// Any permutation is CORRECT (sorting only shrinks per-block Lmax).
// ---------------------------------------------------------------------------
__global__ __launch_bounds__(1024) void k_sort(
    const int* __restrict__ lengths, int* __restrict__ order)
{
  __shared__ int key[2048], val[2048];
  int tid = threadIdx.x;
  for (int v = 0; v < 2; ++v) {
    int i = tid + v * 1024;
    key[i] = (i < S_N) ? lengths[i] : -1;
    val[i] = (i < S_N) ? i : (S_N - 1);
  }
  __syncthreads();
  for (int k = 2; k <= 2048; k <<= 1)
    for (int j = k >> 1; j > 0; j >>= 1) {
      for (int v = 0; v < 2; ++v) {
        int i = tid + v * 1024;
        int ix = i ^ j;
        if (ix > i) {
          bool descRegion = ((i & k) == 0);
          int ki = key[i], kx = key[ix];
          if ((ki < kx) == descRegion) {
            key[i] = kx; key[ix] = ki;
            int tv = val[i]; val[i] = val[ix]; val[ix] = tv;
          }
        }
      }
      __syncthreads();
    }
  for (int v = 0; v < 2; ++v) {
    int i = tid + v * 1024;
    if (i < S_N) order[i] = val[i];
  }
}

// ---------------------------------------------------------------------------
// Kernel 1: word-level LSTM. Blocks 0..64: 16 length-sorted sentences each;
// block 65: target LSTM on the middle sentence. 512 threads / 8 waves,
// 7 n-tiles per wave, single f32x4 acc per tile (spill-free by design).
// gates = [xhi|xlo|hhi|hlo] @ [Wih;Wih;Whh;Whh]^T via MFMA 16x16x32 bf16,
// B (weights) streamed from L2. sG is 8 rows; epilogue in two quad-passes.
// ---------------------------------------------------------------------------
__global__ __launch_bounds__(512) void k_word(
    const float* __restrict__ words, const int* __restrict__ lengths,
    const int* __restrict__ order,
    const float* __restrict__ h0w, const float* __restrict__ c0w,
    const u16* __restrict__ wihb_ctx, const u16* __restrict__ whhb_ctx,
    const float* __restrict__ bih_ctx, const float* __restrict__ bhh_ctx,
    const u16* __restrict__ wihb_tgt, const u16* __restrict__ whhb_tgt,
    const float* __restrict__ bih_tgt, const float* __restrict__ bhh_tgt,
    float* __restrict__ emb)
{
  const int tid = threadIdx.x;
  const int b = blockIdx.x;
  const bool is_tgt = (b == 65);
  const u16* wih = is_tgt ? wihb_tgt : wihb_ctx;
  const u16* whh = is_tgt ? whhb_tgt : whhb_ctx;
  const float* bih = is_tgt ? bih_tgt : bih_ctx;
  const float* bhh = is_tgt ? bhh_tgt : bhh_ctx;

  __shared__ __align__(16) u16 sXhi[16 * KP];
  __shared__ __align__(16) u16 sXlo[16 * KP];
  __shared__ __align__(16) u16 sHi[16 * KP];
  __shared__ __align__(16) u16 sLo[16 * KP];
  __shared__ float sG[8 * SGP];
  __shared__ float sB[4 * H_N];
  __shared__ int sLen[16], sId[16];

  for (int e = tid; e < 16 * KP; e += 512) {
    sXhi[e] = 0; sXlo[e] = 0; sHi[e] = 0; sLo[e] = 0;   // k>=200 pads stay 0
  }
  if (tid < 16) {
    int slot = b * 16 + tid;
    int s = is_tgt ? MID : order[min(slot, S_N - 1)];
    sId[tid] = s;
    sLen[tid] = lengths[s];
  }
  for (int e = tid; e < 4 * H_N; e += 512) sB[e] = bih[e] + bhh[e];
  __syncthreads();

  float creg[7];
#pragma unroll
  for (int r = 0; r < 7; ++r) {
    int e = tid + 512 * r;
    if (e < 16 * H_N) {
      int m = e / H_N, j = e - m * H_N;
      int s = sId[m];
      float h = h0w[(size_t)s * H_N + j];
      u16 hh = f2bf(h);
      sHi[m * KP + j] = hh;
      sLo[m * KP + j] = f2bf(h - bf2f(hh));
      creg[r] = c0w[(size_t)s * H_N + j];
    }
  }
  __syncthreads();
  int Lmax = 1;
  for (int m = 0; m < 16; ++m) Lmax = max(Lmax, sLen[m]);

  const int lane = tid & 63;
  const int wv = tid >> 6;       // 0..7
  const int quad = lane >> 4;
  const int col = lane & 15;
  const int hpass = quad >> 1;   // which epilogue pass this lane writes in

  const u16* aXh = sXhi + col * KP + quad * 8;
  const u16* aXl = sXlo + col * KP + quad * 8;
  const u16* aHh = sHi  + col * KP + quad * 8;
  const u16* aHl = sLo  + col * KP + quad * 8;
  const bf16x8 zz = {};

#pragma unroll 1
  for (int t = 0; t < Lmax; ++t) {
    // stage x_t (fp32 -> hi/lo bf16)
    for (int e = tid; e < 16 * H_N; e += 512) {
      int m = e / H_N, k = e - m * H_N;
      int s = sId[m];
      float v = words[((size_t)s * W_N + t) * H_N + k];
      u16 vh = f2bf(v);
      sXhi[m * KP + k] = vh;
      sXlo[m * KP + k] = f2bf(v - bf2f(vh));
    }
    __syncthreads();

    // hoist A fragments for this step (shared across all 7 tiles)
    bf16x8 A0[7], A1[7], A2[7], A3[7];
#pragma unroll
    for (int kcc = 0; kcc < 7; ++kcc) {
      A0[kcc] = *(const bf16x8*)(aXh + kcc * 32);
      A1[kcc] = *(const bf16x8*)(aXl + kcc * 32);
      A2[kcc] = *(const bf16x8*)(aHh + kcc * 32);
      A3[kcc] = *(const bf16x8*)(aHl + kcc * 32);
    }

    f32x4 acc7[7];
    int ntile = 0;
#pragma unroll 1
    for (int i = 0; i < 7; ++i) {
      int tt = wv + 8 * i;
      if (tt >= 50) break;
      int gate = tt * 16 + col;
      const u16* wrow = wih + (size_t)gate * H_N;
      const u16* hrow = whh + (size_t)gate * H_N;
      f32x4 acc = {0.f, 0.f, 0.f, 0.f};
#pragma unroll
      for (int kcc = 0; kcc < 7; ++kcc) {
        const bool ktail = (kcc == 6) && (quad > 0);
        const int koff = kcc * 32 + quad * 8;
        bf16x8 bw = *(const bf16x8*)(ktail ? wih : (wrow + koff));
        bw = ktail ? zz : bw;
        bf16x8 bh = *(const bf16x8*)(ktail ? whh : (hrow + koff));
        bh = ktail ? zz : bh;
        acc = __builtin_amdgcn_mfma_f32_16x16x32_bf16(A0[kcc], bw, acc, 0, 0, 0);
        acc = __builtin_amdgcn_mfma_f32_16x16x32_bf16(A1[kcc], bw, acc, 0, 0, 0);
        acc = __builtin_amdgcn_mfma_f32_16x16x32_bf16(A2[kcc], bh, acc, 0, 0, 0);
        acc = __builtin_amdgcn_mfma_f32_16x16x32_bf16(A3[kcc], bh, acc, 0, 0, 0);
      }
      acc7[i] = acc;
      ntile = i + 1;
    }

    // epilogue: two passes of 8 sentence-rows through sG
#pragma unroll 1
    for (int h = 0; h < 2; ++h) {
      if (hpass == h) {
        for (int i = 0; i < ntile; ++i) {
          int tt = wv + 8 * i;
#pragma unroll
          for (int r = 0; r < 4; ++r)
            sG[((quad & 1) * 4 + r) * SGP + tt * 16 + col] = acc7[i][r];
        }
      }
      __syncthreads();
#pragma unroll
      for (int rr = 0; rr < 7; ++rr) {
        int e = tid + 512 * rr;
        if (e < 16 * H_N) {
          int m = e / H_N, j = e - m * H_N;
          if ((m >> 3) == h) {
            const float* gRow = sG + (m - 8 * h) * SGP;
            float ig = gRow[j] + sB[j];
            float fg = gRow[H_N + j] + sB[H_N + j];
            float gg = gRow[2 * H_N + j] + sB[2 * H_N + j];
            float og = gRow[3 * H_N + j] + sB[3 * H_N + j];
            float nc = fsigm(fg) * creg[rr] + fsigm(ig) * ftanh(gg);
            float nh = fsigm(og) * ftanh(nc);
            creg[rr] = nc;
            u16 hh = f2bf(nh);
            sHi[m * KP + j] = hh;
            sLo[m * KP + j] = f2bf(nh - bf2f(hh));
            if (t == sLen[m] - 1) {
              int s = sId[m];
              if (is_tgt) {
                if (m == 0) emb[(size_t)MID * H_N + j] = nh;
              } else if (s != MID) {
                emb[(size_t)s * H_N + j] = nh;
              }
            }
          }
        }
      }
      __syncthreads();
    }
  }
}

// ---------------------------------------------------------------------------
// Kernel 2: gx projections via MFMA. Blocks 0..32: prev rows t0=b*16;
// blocks 33..65: post. A = emb rows (hi/lo bf16), B = wih (bf16), +biases.
// ---------------------------------------------------------------------------
__global__ __launch_bounds__(512) void k_gx(
    const float* __restrict__ emb,
    const u16* __restrict__ wihb_prev, const float* __restrict__ bih_prev, const float* __restrict__ bhh_prev,
    const u16* __restrict__ wihb_post, const float* __restrict__ bih_post, const float* __restrict__ bhh_post,
    float* __restrict__ gxp, float* __restrict__ gxq)
{
  const int tid = threadIdx.x;
  const int b = blockIdx.x;
  const bool post = (b >= 33);
  const int t0 = (post ? b - 33 : b) * 16;
  const u16* wih = post ? wihb_post : wihb_prev;
  const float* bih = post ? bih_post : bih_prev;
  const float* bhh = post ? bhh_post : bhh_prev;
  float* out = post ? gxq : gxp;

  __shared__ __align__(16) u16 sEhi[16 * KP];
  __shared__ __align__(16) u16 sElo[16 * KP];
  for (int e = tid; e < 16 * KP; e += 512) { sEhi[e] = 0; sElo[e] = 0; }
  __syncthreads();
  for (int e = tid; e < 16 * H_N; e += 512) {
    int m = e / H_N, k = e - m * H_N;
    int t = t0 + m;
    if (t <= 512) {
      int src = post ? (1024 - t) : t;
      float v = emb[(size_t)src * H_N + k];
      u16 vh = f2bf(v);
      sEhi[m * KP + k] = vh;
      sElo[m * KP + k] = f2bf(v - bf2f(vh));
    }
  }
  __syncthreads();

  const int lane = tid & 63;
  const int wv = tid >> 6;
  const int quad = lane >> 4;
  const int col = lane & 15;
  const u16* aH = sEhi + col * KP + quad * 8;
  const u16* aL = sElo + col * KP + quad * 8;
  const bf16x8 zz = {};

  bf16x8 Ah[7], Al[7];
#pragma unroll
  for (int kcc = 0; kcc < 7; ++kcc) {
    Ah[kcc] = *(const bf16x8*)(aH + kcc * 32);
    Al[kcc] = *(const bf16x8*)(aL + kcc * 32);
  }

#pragma unroll 1
  for (int i = 0; i < 7; ++i) {
    int tt = wv + 8 * i;
    if (tt >= 50) break;
    int gate = tt * 16 + col;
    const u16* wrow = wih + (size_t)gate * H_N;
    f32x4 acc = {0.f, 0.f, 0.f, 0.f};
#pragma unroll
    for (int kcc = 0; kcc < 7; ++kcc) {
      const bool ktail = (kcc == 6) && (quad > 0);
      const int koff = kcc * 32 + quad * 8;
      bf16x8 bw = *(const bf16x8*)(ktail ? wih : (wrow + koff));
      bw = ktail ? zz : bw;
      acc = __builtin_amdgcn_mfma_f32_16x16x32_bf16(Ah[kcc], bw, acc, 0, 0, 0);
      acc = __builtin_amdgcn_mfma_f32_16x16x32_bf16(Al[kcc], bw, acc, 0, 0, 0);
    }
    float bias = bih[gate] + bhh[gate];
#pragma unroll
    for (int r = 0; r < 4; ++r) {
      int t = t0 + quad * 4 + r;
      if (t <= 512) out[(size_t)t * FH_N + gate] = acc[r] + bias;
    }
  }
}

// ---------------------------------------------------------------------------
// Kernel 3: prev (block 0) / post (block 1) sentence LSTMs. 513 serial steps,
// batch=1. Whh bf16 register-resident (afr[13][7], ~412 VGPR @ 1 wave/SIMD,
// no spill). Mixed B: cols 0..7 = h_hi, 8..15 = h_lo; cols 0 and 8 write
// partials to sGa/sGb (no shuffles); update threads add. Fast sigm/tanh.
// ---------------------------------------------------------------------------
__global__ __launch_bounds__(256, 1) void k_sent(
    const u16* __restrict__ whhb_prev, const u16* __restrict__ whhb_post,
    const float* __restrict__ h0p, const float* __restrict__ c0p,
    const float* __restrict__ h0q, const float* __restrict__ c0q,
    const float* __restrict__ gxp, const float* __restrict__ gxq,
    float* __restrict__ outp, float* __restrict__ outq)
{
  const int tid = threadIdx.x;
  const bool post = (blockIdx.x != 0);
  const u16* whh = post ? whhb_post : whhb_prev;
  const float* h0 = post ? h0q : h0p;
  const float* c0 = post ? c0q : c0p;
  const float* gx = post ? gxq : gxp;
  float* outv = post ? outq : outp;

  __shared__ __align__(16) u16 sHi[224];
  __shared__ __align__(16) u16 sLo[224];
  __shared__ float sGa[FH_N];
  __shared__ float sGb[FH_N];

  const int lane = tid & 63;
  const int wv = tid >> 6;
  const int quad = lane >> 4;
  const int col = lane & 15;
  const bf16x8 zz = {};

  bf16x8 afr[13][7];
#pragma unroll
  for (int i = 0; i < 13; ++i) {
    int tt = wv + 4 * i;
#pragma unroll
    for (int kcc = 0; kcc < 7; ++kcc) {
      int k0 = kcc * 32 + quad * 8;
      bool valid = (tt < 50) && (k0 < H_N);
      const u16* p = valid ? (whh + (size_t)(tt * 16 + col) * H_N + k0) : whh;
      bf16x8 v = *(const bf16x8*)p;
      afr[i][kcc] = valid ? v : zz;
    }
  }

  if (tid < 224) { sHi[tid] = 0; sLo[tid] = 0; }
  float c = 0.f, last_h = 0.f;
  if (tid < H_N) {
    float h = h0[tid];
    u16 hh = f2bf(h);
    sHi[tid] = hh;
    sLo[tid] = f2bf(h - bf2f(hh));
    c = c0[tid];
  }
  __syncthreads();

  const u16* hb = ((lane & 8) ? sLo : sHi) + quad * 8;
  const bool wrA = (col == 0), wrB = (col == 8);

#pragma unroll 1
  for (int t = 0; t < 513; ++t) {
    float g0 = 0.f, g1 = 0.f, g2 = 0.f, g3 = 0.f;
    if (tid < H_N) {
      const float* g = gx + (size_t)t * FH_N;
      g0 = g[tid]; g1 = g[H_N + tid]; g2 = g[2 * H_N + tid]; g3 = g[3 * H_N + tid];
    }

    bf16x8 bfr[7];
#pragma unroll
    for (int kcc = 0; kcc < 7; ++kcc) bfr[kcc] = *(const bf16x8*)(hb + kcc * 32);

#pragma unroll
    for (int i = 0; i < 13; ++i) {
      int tt = wv + 4 * i;
      f32x4 acc = {0.f, 0.f, 0.f, 0.f};
#pragma unroll
      for (int kcc = 0; kcc < 7; ++kcc)
        acc = __builtin_amdgcn_mfma_f32_16x16x32_bf16(afr[i][kcc], bfr[kcc], acc, 0, 0, 0);
      if (tt < 50) {
        if (wrA) {
#pragma unroll
          for (int r = 0; r < 4; ++r) sGa[tt * 16 + quad * 4 + r] = acc[r];
        } else if (wrB) {
#pragma unroll
          for (int r = 0; r < 4; ++r) sGb[tt * 16 + quad * 4 + r] = acc[r];
        }
      }
    }
    __syncthreads();

    if (tid < H_N) {
      float ig = sGa[tid] + sGb[tid] + g0;
      float fg = sGa[H_N + tid] + sGb[H_N + tid] + g1;
      float gg = sGa[2 * H_N + tid] + sGb[2 * H_N + tid] + g2;
      float og = sGa[3 * H_N + tid] + sGb[3 * H_N + tid] + g3;
      float nc = fsigm(fg) * c + fsigm(ig) * ftanh(gg);
      float nh = fsigm(og) * ftanh(nc);
      c = nc;
      last_h = nh;
      u16 hh = f2bf(nh);
      sHi[tid] = hh;
      sLo[tid] = f2bf(nh - bf2f(hh));
    }
    __syncthreads();
  }
  if (tid < H_N) outv[tid] = last_h;
}

// ---------------------------------------------------------------------------
// Kernel 4: out = [prev_out ; post_out] @ fc_w^T + fc_b  (fp32 exact)
// ---------------------------------------------------------------------------
__global__ __launch_bounds__(256) void k_fc(
    const float* __restrict__ pout, const float* __restrict__ qout,
    const float* __restrict__ fc_w, const float* __restrict__ fc_b,
    float* __restrict__ out)
{
  const int tid = threadIdx.x;
  if (tid < H_N) {
    float d = fc_b[tid];
    const float* wr = fc_w + (size_t)tid * 2 * H_N;
    for (int k = 0; k < H_N; ++k) d += pout[k] * wr[k];
    for (int k = 0; k < H_N; ++k) d += qout[k] * wr[H_N + k];
    out[tid] = d;
  }
}

extern "C" void kernel_launch(void* const* d_in, const int* in_sizes, int n_in,
                              void* d_out, int out_size, void* d_ws, size_t ws_size,
                              hipStream_t stream) {
  const float* words   = (const float*)d_in[0];
  const int*   lengths = (const int*)d_in[1];
  const float* h0w = (const float*)d_in[2];
  const float* c0w = (const float*)d_in[3];
  const float* h0p = (const float*)d_in[4];
  const float* c0p = (const float*)d_in[5];
  const float* h0q = (const float*)d_in[6];
  const float* c0q = (const float*)d_in[7];
  const float* wih_ctx = (const float*)d_in[8];
  const float* whh_ctx = (const float*)d_in[9];
  const float* bih_ctx = (const float*)d_in[10];
  const float* bhh_ctx = (const float*)d_in[11];
  const float* wih_tgt = (const float*)d_in[12];
  const float* whh_tgt = (const float*)d_in[13];
  const float* bih_tgt = (const float*)d_in[14];
  const float* bhh_tgt = (const float*)d_in[15];
  const float* wih_prev = (const float*)d_in[16];
  const float* whh_prev = (const float*)d_in[17];
  const float* bih_prev = (const float*)d_in[18];
  const float* bhh_prev = (const float*)d_in[19];
  const float* wih_post = (const float*)d_in[20];
  const float* whh_post = (const float*)d_in[21];
  const float* bih_post = (const float*)d_in[22];
  const float* bhh_post = (const float*)d_in[23];
  const float* fc_w = (const float*)d_in[24];
  const float* fc_b = (const float*)d_in[25];

  float* ws = (float*)d_ws;
  float* emb = ws;                   // 205000 floats
  float* gxp = ws + 205000;          // 410400
  float* gxq = ws + 615400;          // 410400
  float* po  = ws + 1025800;         // 200
  float* qo  = ws + 1026000;         // 200
  int*   order = (int*)(ws + 1026200);   // 1025 ints
  u16*   wb = (u16*)(ws + 1027232);      // 8*160000 u16, 16B-aligned
  u16* wihb_ctx  = wb;
  u16* whhb_ctx  = wb + WELEM;
  u16* wihb_tgt  = wb + 2 * WELEM;
  u16* whhb_tgt  = wb + 3 * WELEM;
  u16* whhb_prev = wb + 4 * WELEM;
  u16* whhb_post = wb + 5 * WELEM;
  u16* wihb_prev = wb + 6 * WELEM;
  u16* wihb_post = wb + 7 * WELEM;
  (void)in_sizes; (void)n_in; (void)out_size; (void)ws_size;

  k_w2b<<<(8 * WELEM + 255) / 256, 256, 0, stream>>>(
      wih_ctx, whh_ctx, wih_tgt, whh_tgt, whh_prev, whh_post,
      wih_prev, wih_post, wb);
  k_sort<<<1, 1024, 0, stream>>>(lengths, order);
  k_word<<<66, 512, 0, stream>>>(words, lengths, order, h0w, c0w,
                                 wihb_ctx, whhb_ctx, bih_ctx, bhh_ctx,
                                 wihb_tgt, whhb_tgt, bih_tgt, bhh_tgt, emb);
  k_gx<<<66, 512, 0, stream>>>(emb, wihb_prev, bih_prev, bhh_prev,
                               wihb_post, bih_post, bhh_post, gxp, gxq);
  k_sent<<<2, 256, 0, stream>>>(whhb_prev, whhb_post, h0p, c0p, h0q, c0q,
                                gxp, gxq, po, qo);
  k_fc<<<1, 256, 0, stream>>>(po, qo, fc_w, fc_b, (float*)d_out);
}